// Round 1
// baseline (132.268 us; speedup 1.0000x reference)
//
#include <hip/hip_runtime.h>
#include <hip/hip_bf16.h>
#include <stdint.h>

#define FEAT 1024
#define NALL 1000
#define NPAD 1120
#define NCLS 100

typedef __attribute__((ext_vector_type(8))) short short8;
typedef __attribute__((ext_vector_type(4))) float f32x4;
typedef __attribute__((ext_vector_type(4))) unsigned short us4;

__device__ __forceinline__ unsigned short f2bf(float f) {
    union { float f; uint32_t u; } v; v.f = f;
    uint32_t u = v.u;
    return (unsigned short)((u + 0x7FFFu + ((u >> 16) & 1u)) >> 16);
}

__device__ __forceinline__ void gload16(const void* g, void* l) {
    __builtin_amdgcn_global_load_lds((__attribute__((address_space(1))) void*)g,
                                     (__attribute__((address_space(3))) void*)l,
                                     16, 0, 0);
}

// K1: x (16384x1024 f32) -> bf16, plus row sum-of-squares
__global__ __launch_bounds__(256) void k_prep_x(const float* __restrict__ x,
                                                unsigned short* __restrict__ xb,
                                                float* __restrict__ xsq) {
    int row = blockIdx.x * 4 + (threadIdx.x >> 6);
    int lane = threadIdx.x & 63;
    const float4* xr = (const float4*)(x + (size_t)row * FEAT);
    float s = 0.f;
#pragma unroll
    for (int i = 0; i < 4; ++i) {
        float4 v = xr[lane + i * 64];
        s += v.x * v.x + v.y * v.y + v.z * v.z + v.w * v.w;
        us4 o;
        o[0] = f2bf(v.x); o[1] = f2bf(v.y); o[2] = f2bf(v.z); o[3] = f2bf(v.w);
        *(us4*)(xb + (size_t)row * FEAT + (size_t)(lane + i * 64) * 4) = o;
    }
#pragma unroll
    for (int off = 32; off; off >>= 1) s += __shfl_xor(s, off);
    if (lane == 0) xsq[row] = s;
}

// K2a: protos (1000x1024 f32) -> bf16 padded to 1024 rows (pad = 0)
__global__ __launch_bounds__(256) void k_prep_protos(const float* __restrict__ p,
                                                     unsigned short* __restrict__ pb) {
    int row = blockIdx.x;
    int t = threadIdx.x;
    us4 o;
    if (row < NALL) {
        float4 v = ((const float4*)(p + (size_t)row * FEAT))[t];
        o[0] = f2bf(v.x); o[1] = f2bf(v.y); o[2] = f2bf(v.z); o[3] = f2bf(v.w);
    } else {
        o[0] = 0; o[1] = 0; o[2] = 0; o[3] = 0;
    }
    *(us4*)(pb + (size_t)row * FEAT + (size_t)t * 4) = o;
}

// K2b: enc_w (1024x1024 f32) -> transposed bf16 (wt[n][k] = enc_w[k][n])
__global__ __launch_bounds__(256) void k_transpose_w(const float* __restrict__ w,
                                                     unsigned short* __restrict__ wt) {
    __shared__ float tile[32][33];
    int bx = blockIdx.x, by = blockIdx.y;
    int tx = threadIdx.x & 31, ty = threadIdx.x >> 5;
#pragma unroll
    for (int i = 0; i < 4; ++i) {
        int r = by * 32 + ty + i * 8;
        tile[ty + i * 8][tx] = w[(size_t)r * FEAT + bx * 32 + tx];
    }
    __syncthreads();
#pragma unroll
    for (int i = 0; i < 4; ++i) {
        int r = bx * 32 + ty + i * 8;
        wt[(size_t)r * FEAT + by * 32 + tx] = f2bf(tile[tx][ty + i * 8]);
    }
}

// K2c: encoder GEMM: ep = protos @ enc_w + b. A=protosb[1024][1024], B=enc_wT[1024][1024].
// Writes epb rows in class-major permuted order: n' = (n%100)*10 + n/100.
__global__ __launch_bounds__(256) void k_enc_gemm(const unsigned short* __restrict__ A,
                                                  const unsigned short* __restrict__ B,
                                                  const float* __restrict__ bias,
                                                  unsigned short* __restrict__ epb) {
    __shared__ __align__(16) char smem[32768];
    int bm0 = (blockIdx.x >> 3) * 128;
    int bn0 = (blockIdx.x & 7) * 128;
    int tid = threadIdx.x, lane = tid & 63, wid = tid >> 6;
    int wm = wid >> 1, wn = wid & 1;
    int ls = lane >> 4, lf = lane & 15;
    f32x4 acc[4][4] = {};
    for (int k0 = 0; k0 < FEAT; k0 += 64) {
        __syncthreads();
#pragma unroll
        for (int i = 0; i < 4; ++i) {
            int ci = wid + i * 4;
            int r = ci * 8 + (lane >> 3), c = (lane & 7) * 8;
            gload16(A + (size_t)(bm0 + r) * FEAT + k0 + c, smem + ci * 1024);
            gload16(B + (size_t)(bn0 + r) * FEAT + k0 + c, smem + 16384 + ci * 1024);
        }
        __syncthreads();
#pragma unroll
        for (int kk = 0; kk < 64; kk += 32) {
            short8 a[4], b[4];
#pragma unroll
            for (int f = 0; f < 4; ++f) {
                a[f] = *(const short8*)(smem + (wm * 64 + f * 16 + lf) * 128 + (kk + ls * 8) * 2);
                b[f] = *(const short8*)(smem + 16384 + (wn * 64 + f * 16 + lf) * 128 + (kk + ls * 8) * 2);
            }
#pragma unroll
            for (int fm = 0; fm < 4; ++fm)
#pragma unroll
                for (int fn = 0; fn < 4; ++fn)
                    acc[fm][fn] = __builtin_amdgcn_mfma_f32_16x16x32_bf16(a[fm], b[fn], acc[fm][fn], 0, 0, 0);
        }
    }
    int tr = ls * 4, tc = lf;
#pragma unroll
    for (int fn = 0; fn < 4; ++fn) {
        int col = bn0 + wn * 64 + fn * 16 + tc;
        float bb = bias[col];
#pragma unroll
        for (int fm = 0; fm < 4; ++fm) {
#pragma unroll
            for (int r = 0; r < 4; ++r) {
                int row = bm0 + wm * 64 + fm * 16 + tr + r;
                if (row < NALL) {
                    int pr = (row % 100) * 10 + row / 100;
                    epb[(size_t)pr * FEAT + col] = f2bf(acc[fm][fn][r] + bb);
                }
            }
        }
    }
}

// K2d: p_sq per (permuted) ep row; pad rows get 1e30
__global__ __launch_bounds__(256) void k_psq(const unsigned short* __restrict__ epb,
                                             float* __restrict__ psq) {
    int row = blockIdx.x * 4 + (threadIdx.x >> 6);
    int lane = threadIdx.x & 63;
    if (row >= NPAD) return;
    float s = 0.f;
    const short8* r8 = (const short8*)(epb + (size_t)row * FEAT);
#pragma unroll
    for (int i = 0; i < 2; ++i) {
        short8 v = r8[lane + i * 64];
#pragma unroll
        for (int j = 0; j < 8; ++j) {
            union { uint32_t u; float f; } c;
            c.u = ((uint32_t)(unsigned short)v[j]) << 16;
            s += c.f * c.f;
        }
    }
#pragma unroll
    for (int off = 32; off; off >>= 1) s += __shfl_xor(s, off);
    if (lane == 0) psq[row] = (row < NALL) ? s : 1e30f;
}

// K3: main GEMM (16384 x 1120 x 1024) + fused sqrt + min-over-10-protos epilogue.
// BM=128, BN=160 (16 classes x 10 protos), BK=64, 4 waves (2x2), frags 4x5.
__global__ __launch_bounds__(256) void k_main(const unsigned short* __restrict__ xb,
                                              const unsigned short* __restrict__ epb,
                                              const float* __restrict__ xsq,
                                              const float* __restrict__ psq,
                                              float* __restrict__ out) {
    __shared__ __align__(16) char smem[43008];
    int bid = blockIdx.x;                       // 896 blocks
    int swz = (bid & 7) * 112 + (bid >> 3);     // XCD-chunk swizzle (896 % 8 == 0)
    int bm0 = (swz / 7) * 128;
    int bn0 = (swz % 7) * 160;
    int tid = threadIdx.x, lane = tid & 63, wid = tid >> 6;
    int wm = wid >> 1, wn = wid & 1;
    int ls = lane >> 4, lf = lane & 15;
    float* xsq_s = (float*)(smem + 41216);
    float* psq_s = (float*)(smem + 41728);
    if (tid < 128) xsq_s[tid] = xsq[bm0 + tid];
    if (tid < 160) psq_s[tid] = psq[bn0 + tid];
    f32x4 acc[4][5] = {};
    for (int k0 = 0; k0 < FEAT; k0 += 64) {
        __syncthreads();
#pragma unroll
        for (int i = 0; i < 4; ++i) {
            int ci = wid + i * 4;
            gload16(xb + (size_t)(bm0 + ci * 8 + (lane >> 3)) * FEAT + k0 + (lane & 7) * 8,
                    smem + ci * 1024);
        }
#pragma unroll
        for (int i = 0; i < 5; ++i) {
            int ci = wid + i * 4;
            gload16(epb + (size_t)(bn0 + ci * 8 + (lane >> 3)) * FEAT + k0 + (lane & 7) * 8,
                    smem + 16384 + ci * 1024);
        }
        __syncthreads();
#pragma unroll
        for (int kk = 0; kk < 64; kk += 32) {
            short8 a[4], b[5];
#pragma unroll
            for (int f = 0; f < 4; ++f)
                a[f] = *(const short8*)(smem + (wm * 64 + f * 16 + lf) * 128 + (kk + ls * 8) * 2);
#pragma unroll
            for (int f = 0; f < 5; ++f)
                b[f] = *(const short8*)(smem + 16384 + (wn * 80 + f * 16 + lf) * 128 + (kk + ls * 8) * 2);
#pragma unroll
            for (int fm = 0; fm < 4; ++fm)
#pragma unroll
                for (int fn = 0; fn < 5; ++fn)
                    acc[fm][fn] = __builtin_amdgcn_mfma_f32_16x16x32_bf16(a[fm], b[fn], acc[fm][fn], 0, 0, 0);
        }
    }
    // epilogue: d = sqrt(max(xsq - 2*dot + psq, 0)); min over groups of 10 columns
    float* dls = (float*)smem;  // [64][161] f32, two passes over fm halves
    int tr = ls * 4, tc = lf;
    int cls0 = bn0 / 10;  // = ntile * 16
#pragma unroll
    for (int p = 0; p < 2; ++p) {
        __syncthreads();
#pragma unroll
        for (int f2 = 0; f2 < 2; ++f2) {
            int fm = p * 2 + f2;
#pragma unroll
            for (int fn = 0; fn < 5; ++fn) {
                int col = wn * 80 + fn * 16 + tc;
                float pq = psq_s[col];
#pragma unroll
                for (int r = 0; r < 4; ++r) {
                    float d2 = xsq_s[wm * 64 + fm * 16 + tr + r] - 2.f * acc[fm][fn][r] + pq;
                    dls[(wm * 32 + f2 * 16 + tr + r) * 161 + col] = sqrtf(fmaxf(d2, 0.f));
                }
            }
        }
        __syncthreads();
#pragma unroll
        for (int tI = 0; tI < 4; ++tI) {
            int task = tid + tI * 256;
            int rr = task >> 4, cl = task & 15;
            float m = 1e30f;
#pragma unroll
            for (int j = 0; j < 10; ++j) m = fminf(m, dls[rr * 161 + cl * 10 + j]);
            int grow = bm0 + (rr >> 5) * 64 + p * 32 + (rr & 31);
            int gcls = cls0 + cl;
            if (gcls < NCLS) out[(size_t)grow * NCLS + gcls] = m;
        }
    }
}

extern "C" void kernel_launch(void* const* d_in, const int* in_sizes, int n_in,
                              void* d_out, int out_size, void* d_ws, size_t ws_size,
                              hipStream_t stream) {
    const float* x      = (const float*)d_in[0];
    const float* protos = (const float*)d_in[1];
    const float* enc_w  = (const float*)d_in[2];
    const float* enc_b  = (const float*)d_in[3];
    float* out = (float*)d_out;
    char* ws = (char*)d_ws;

    unsigned short* xb  = (unsigned short*)ws;                   // 16384*1024*2 = 33554432
    unsigned short* epb = (unsigned short*)(ws + 33554432);      // 1120*1024*2  = 2293760
    unsigned short* prb = (unsigned short*)(ws + 35848192);      // 1024*1024*2  = 2097152
    unsigned short* wtb = (unsigned short*)(ws + 37945344);      // 1024*1024*2  = 2097152
    float* xsq = (float*)(ws + 40042496);                        // 16384*4
    float* psq = (float*)(ws + 40108032);                        // 1120*4

    // zero the padded ep rows (1000..1119) so staging reads defined data
    hipMemsetAsync(epb + (size_t)1000 * FEAT, 0, (size_t)120 * FEAT * 2, stream);

    k_prep_x<<<4096, 256, 0, stream>>>(x, xb, xsq);
    k_prep_protos<<<1024, 256, 0, stream>>>(protos, prb);
    k_transpose_w<<<dim3(32, 32), 256, 0, stream>>>(enc_w, wtb);
    k_enc_gemm<<<64, 256, 0, stream>>>(prb, wtb, enc_b, epb);
    k_psq<<<280, 256, 0, stream>>>(epb, psq);
    k_main<<<896, 256, 0, stream>>>(xb, epb, xsq, psq, out);
}

// Round 2
// 109.850 us; speedup vs baseline: 1.2041x; 1.2041x over previous
//
#include <hip/hip_runtime.h>
#include <hip/hip_bf16.h>
#include <stdint.h>

#define FEAT 1024
#define NALL 1000
#define NPAD 1120
#define NCLS 100

typedef __attribute__((ext_vector_type(8))) short short8;
typedef __attribute__((ext_vector_type(4))) float f32x4;
typedef __attribute__((ext_vector_type(4))) unsigned short us4;

__device__ __forceinline__ unsigned short f2bf(float f) {
    union { float f; uint32_t u; } v; v.f = f;
    uint32_t u = v.u;
    return (unsigned short)((u + 0x7FFFu + ((u >> 16) & 1u)) >> 16);
}

__device__ __forceinline__ void gload16(const void* g, void* l) {
    __builtin_amdgcn_global_load_lds((__attribute__((address_space(1))) void*)g,
                                     (__attribute__((address_space(3))) void*)l,
                                     16, 0, 0);
}

// K1: x (16384x1024 f32) -> bf16, plus row sum-of-squares
__global__ __launch_bounds__(256) void k_prep_x(const float* __restrict__ x,
                                                unsigned short* __restrict__ xb,
                                                float* __restrict__ xsq) {
    int row = blockIdx.x * 4 + (threadIdx.x >> 6);
    int lane = threadIdx.x & 63;
    const float4* xr = (const float4*)(x + (size_t)row * FEAT);
    float s = 0.f;
#pragma unroll
    for (int i = 0; i < 4; ++i) {
        float4 v = xr[lane + i * 64];
        s += v.x * v.x + v.y * v.y + v.z * v.z + v.w * v.w;
        us4 o;
        o[0] = f2bf(v.x); o[1] = f2bf(v.y); o[2] = f2bf(v.z); o[3] = f2bf(v.w);
        *(us4*)(xb + (size_t)row * FEAT + (size_t)(lane + i * 64) * 4) = o;
    }
#pragma unroll
    for (int off = 32; off; off >>= 1) s += __shfl_xor(s, off);
    if (lane == 0) xsq[row] = s;
}

// K2a: protos (1000x1024 f32) -> bf16 padded to 1024 rows (pad = 0)
__global__ __launch_bounds__(256) void k_prep_protos(const float* __restrict__ p,
                                                     unsigned short* __restrict__ pb) {
    int row = blockIdx.x;
    int t = threadIdx.x;
    us4 o;
    if (row < NALL) {
        float4 v = ((const float4*)(p + (size_t)row * FEAT))[t];
        o[0] = f2bf(v.x); o[1] = f2bf(v.y); o[2] = f2bf(v.z); o[3] = f2bf(v.w);
    } else {
        o[0] = 0; o[1] = 0; o[2] = 0; o[3] = 0;
    }
    *(us4*)(pb + (size_t)row * FEAT + (size_t)t * 4) = o;
}

// K2b: enc_w (1024x1024 f32) -> transposed bf16 (wt[n][k] = enc_w[k][n])
__global__ __launch_bounds__(256) void k_transpose_w(const float* __restrict__ w,
                                                     unsigned short* __restrict__ wt) {
    __shared__ float tile[32][33];
    int bx = blockIdx.x, by = blockIdx.y;
    int tx = threadIdx.x & 31, ty = threadIdx.x >> 5;
#pragma unroll
    for (int i = 0; i < 4; ++i) {
        int r = by * 32 + ty + i * 8;
        tile[ty + i * 8][tx] = w[(size_t)r * FEAT + bx * 32 + tx];
    }
    __syncthreads();
#pragma unroll
    for (int i = 0; i < 4; ++i) {
        int r = bx * 32 + ty + i * 8;
        wt[(size_t)r * FEAT + by * 32 + tx] = f2bf(tile[tx][ty + i * 8]);
    }
}

// K2c: encoder GEMM: ep = protos @ enc_w + b. Writes epb rows in class-major
// permuted order: n' = (n%100)*10 + n/100.
__global__ __launch_bounds__(256) void k_enc_gemm(const unsigned short* __restrict__ A,
                                                  const unsigned short* __restrict__ B,
                                                  const float* __restrict__ bias,
                                                  unsigned short* __restrict__ epb) {
    __shared__ __align__(16) char smem[32768];
    int bm0 = (blockIdx.x >> 3) * 128;
    int bn0 = (blockIdx.x & 7) * 128;
    int tid = threadIdx.x, lane = tid & 63, wid = tid >> 6;
    int wm = wid >> 1, wn = wid & 1;
    int ls = lane >> 4, lf = lane & 15;
    f32x4 acc[4][4] = {};
    for (int k0 = 0; k0 < FEAT; k0 += 64) {
        __syncthreads();
#pragma unroll
        for (int i = 0; i < 4; ++i) {
            int ci = wid + i * 4;
            int r = ci * 8 + (lane >> 3), c = (lane & 7) * 8;
            gload16(A + (size_t)(bm0 + r) * FEAT + k0 + c, smem + ci * 1024);
            gload16(B + (size_t)(bn0 + r) * FEAT + k0 + c, smem + 16384 + ci * 1024);
        }
        __syncthreads();
#pragma unroll
        for (int kk = 0; kk < 64; kk += 32) {
            short8 a[4], b[4];
#pragma unroll
            for (int f = 0; f < 4; ++f) {
                a[f] = *(const short8*)(smem + (wm * 64 + f * 16 + lf) * 128 + (kk + ls * 8) * 2);
                b[f] = *(const short8*)(smem + 16384 + (wn * 64 + f * 16 + lf) * 128 + (kk + ls * 8) * 2);
            }
#pragma unroll
            for (int fm = 0; fm < 4; ++fm)
#pragma unroll
                for (int fn = 0; fn < 4; ++fn)
                    acc[fm][fn] = __builtin_amdgcn_mfma_f32_16x16x32_bf16(a[fm], b[fn], acc[fm][fn], 0, 0, 0);
        }
    }
    int tr = ls * 4, tc = lf;
#pragma unroll
    for (int fn = 0; fn < 4; ++fn) {
        int col = bn0 + wn * 64 + fn * 16 + tc;
        float bb = bias[col];
#pragma unroll
        for (int fm = 0; fm < 4; ++fm) {
#pragma unroll
            for (int r = 0; r < 4; ++r) {
                int row = bm0 + wm * 64 + fm * 16 + tr + r;
                if (row < NALL) {
                    int pr = (row % 100) * 10 + row / 100;
                    epb[(size_t)pr * FEAT + col] = f2bf(acc[fm][fn][r] + bb);
                }
            }
        }
    }
}

// K2d: p_sq per (permuted) ep row; pad rows get 1e30
__global__ __launch_bounds__(256) void k_psq(const unsigned short* __restrict__ epb,
                                             float* __restrict__ psq) {
    int row = blockIdx.x * 4 + (threadIdx.x >> 6);
    int lane = threadIdx.x & 63;
    if (row >= NPAD) return;
    float s = 0.f;
    const short8* r8 = (const short8*)(epb + (size_t)row * FEAT);
#pragma unroll
    for (int i = 0; i < 2; ++i) {
        short8 v = r8[lane + i * 64];
#pragma unroll
        for (int j = 0; j < 8; ++j) {
            union { uint32_t u; float f; } c;
            c.u = ((uint32_t)(unsigned short)v[j]) << 16;
            s += c.f * c.f;
        }
    }
#pragma unroll
    for (int off = 32; off; off >>= 1) s += __shfl_xor(s, off);
    if (lane == 0) psq[row] = (row < NALL) ? s : 1e30f;
}

// K3: main GEMM (16384 x 1120 x 1024) + fused sqrt + min-over-10-protos epilogue.
// BM=128, BN=160, BK=64, 4 waves (2x2), frags 4x5.
// Double-buffered LDS (T3-minimum 2-phase) + T2 XOR column-block swizzle
// (pre-swizzled global source, swizzled ds_read — rule 21).
__global__ __launch_bounds__(256) void k_main(const unsigned short* __restrict__ xb,
                                              const unsigned short* __restrict__ epb,
                                              const float* __restrict__ xsq,
                                              const float* __restrict__ psq,
                                              float* __restrict__ out) {
    __shared__ __align__(16) char smem[74880];
    // buf[c] at c*36864: A tile [128][64] at +0 (16KB), B tile [160][64] at +16384 (20KB)
    const int bid = blockIdx.x;                       // 896 blocks
    const int swz = (bid & 7) * 112 + (bid >> 3);     // XCD-chunk swizzle (896 % 8 == 0)
    const int bm0 = (swz / 7) * 128;
    const int bn0 = (swz % 7) * 160;
    const int tid = threadIdx.x, lane = tid & 63, wid = tid >> 6;
    const int wm = wid >> 1, wn = wid & 1;
    const int ls = lane >> 4, lf = lane & 15;
    float* xsq_s = (float*)(smem + 73728);
    float* psq_s = (float*)(smem + 74240);
    if (tid < 128) xsq_s[tid] = xsq[bm0 + tid];
    if (tid < 160) psq_s[tid] = psq[bn0 + tid];

    // staging source pointers: lane (r=lane>>3, cb=lane&7) loads logical column
    // block (cb ^ r) so that the linear LDS write leaves data at the swizzled slot.
    const int sr = lane >> 3, scb = lane & 7;
    const int scol = ((scb ^ sr) << 3);               // element offset within 64-col tile
    const unsigned short* aptr[4];
    const unsigned short* bptr[5];
#pragma unroll
    for (int i = 0; i < 4; ++i)
        aptr[i] = xb + (size_t)(bm0 + (wid + i * 4) * 8 + sr) * FEAT + scol;
#pragma unroll
    for (int i = 0; i < 5; ++i)
        bptr[i] = epb + (size_t)(bn0 + (wid + i * 4) * 8 + sr) * FEAT + scol;

    // swizzled read offsets: addr = row*128 + ((CB ^ (row&7)) << 4), row&7 == lf&7
    int raA[4], raB[5];
#pragma unroll
    for (int f = 0; f < 4; ++f) raA[f] = (wm * 64 + f * 16 + lf) * 128;
#pragma unroll
    for (int f = 0; f < 5; ++f) raB[f] = 16384 + (wn * 80 + f * 16 + lf) * 128;
    const int sw = lf & 7;

    f32x4 acc[4][5] = {};

#define STAGE(T, CUR) do {                                                     \
    char* lb_ = smem + (CUR) * 36864;                                          \
    _Pragma("unroll")                                                          \
    for (int i_ = 0; i_ < 4; ++i_)                                             \
        gload16(aptr[i_] + (T) * 64, lb_ + (wid + i_ * 4) * 1024);             \
    _Pragma("unroll")                                                          \
    for (int i_ = 0; i_ < 5; ++i_)                                             \
        gload16(bptr[i_] + (T) * 64, lb_ + 16384 + (wid + i_ * 4) * 1024);     \
} while (0)

    STAGE(0, 0);
    __syncthreads();
#pragma unroll
    for (int t = 0; t < 16; ++t) {
        const int cur = t & 1;
        if (t < 15) STAGE(t + 1, cur ^ 1);
        const char* base = (const char*)smem + cur * 36864;
#pragma unroll
        for (int kk2 = 0; kk2 < 2; ++kk2) {
            const int off = (((kk2 * 4 + ls) ^ sw) << 4);
            short8 a[4], b[5];
#pragma unroll
            for (int f = 0; f < 4; ++f)
                a[f] = *(const short8*)(base + raA[f] + off);
#pragma unroll
            for (int f = 0; f < 5; ++f)
                b[f] = *(const short8*)(base + raB[f] + off);
#pragma unroll
            for (int fm = 0; fm < 4; ++fm)
#pragma unroll
                for (int fn = 0; fn < 5; ++fn)
                    acc[fm][fn] = __builtin_amdgcn_mfma_f32_16x16x32_bf16(a[fm], b[fn], acc[fm][fn], 0, 0, 0);
        }
        __syncthreads();
    }
#undef STAGE

    // epilogue: d = sqrt(max(xsq - 2*dot + psq, 0)); min over groups of 10 columns
    float* dls = (float*)smem;  // [64][161] f32, two passes over fm halves
    const int tr = ls * 4, tc = lf;
    const int cls0 = bn0 / 10;  // = ntile * 16
#pragma unroll
    for (int p = 0; p < 2; ++p) {
        __syncthreads();
#pragma unroll
        for (int f2 = 0; f2 < 2; ++f2) {
            int fm = p * 2 + f2;
#pragma unroll
            for (int fn = 0; fn < 5; ++fn) {
                int col = wn * 80 + fn * 16 + tc;
                float pq = psq_s[col];
#pragma unroll
                for (int r = 0; r < 4; ++r) {
                    float d2 = xsq_s[wm * 64 + fm * 16 + tr + r] - 2.f * acc[fm][fn][r] + pq;
                    dls[(wm * 32 + f2 * 16 + tr + r) * 161 + col] = sqrtf(fmaxf(d2, 0.f));
                }
            }
        }
        __syncthreads();
#pragma unroll
        for (int tI = 0; tI < 4; ++tI) {
            int task = tid + tI * 256;
            int rr = task >> 4, cl = task & 15;
            float m = 1e30f;
#pragma unroll
            for (int j = 0; j < 10; ++j) m = fminf(m, dls[rr * 161 + cl * 10 + j]);
            int grow = bm0 + (rr >> 5) * 64 + p * 32 + (rr & 31);
            int gcls = cls0 + cl;
            if (gcls < NCLS) out[(size_t)grow * NCLS + gcls] = m;
        }
    }
}

extern "C" void kernel_launch(void* const* d_in, const int* in_sizes, int n_in,
                              void* d_out, int out_size, void* d_ws, size_t ws_size,
                              hipStream_t stream) {
    const float* x      = (const float*)d_in[0];
    const float* protos = (const float*)d_in[1];
    const float* enc_w  = (const float*)d_in[2];
    const float* enc_b  = (const float*)d_in[3];
    float* out = (float*)d_out;
    char* ws = (char*)d_ws;

    unsigned short* xb  = (unsigned short*)ws;                   // 16384*1024*2 = 33554432
    unsigned short* epb = (unsigned short*)(ws + 33554432);      // 1120*1024*2  = 2293760
    unsigned short* prb = (unsigned short*)(ws + 35848192);      // 1024*1024*2  = 2097152
    unsigned short* wtb = (unsigned short*)(ws + 37945344);      // 1024*1024*2  = 2097152
    float* xsq = (float*)(ws + 40042496);                        // 16384*4
    float* psq = (float*)(ws + 40108032);                        // 1120*4

    // zero the padded ep rows (1000..1119) so staging reads defined data
    hipMemsetAsync(epb + (size_t)1000 * FEAT, 0, (size_t)120 * FEAT * 2, stream);

    k_prep_x<<<4096, 256, 0, stream>>>(x, xb, xsq);
    k_prep_protos<<<1024, 256, 0, stream>>>(protos, prb);
    k_transpose_w<<<dim3(32, 32), 256, 0, stream>>>(enc_w, wtb);
    k_enc_gemm<<<64, 256, 0, stream>>>(prb, wtb, enc_b, epb);
    k_psq<<<280, 256, 0, stream>>>(epb, psq);
    k_main<<<896, 256, 0, stream>>>(xb, epb, xsq, psq, out);
}